// Round 4
// baseline (923.405 us; speedup 1.0000x reference)
//
#include <hip/hip_runtime.h>

constexpr int H = 128;
constexpr int F = 9;
constexpr float BN_EPS = 1e-5f;
constexpr int NBMAX = 512;      // max dst buckets (256 nodes each, N <= 131072)

typedef _Float16 f16x8 __attribute__((ext_vector_type(8)));
typedef _Float16 f16x4 __attribute__((ext_vector_type(4)));
typedef float    f32x4 __attribute__((ext_vector_type(4)));

// ---------------- bucketed CSR build (no per-node global atomics) ----------------

// Pass A: bucket histogram (bucket = dst >> 8)
__global__ __launch_bounds__(256) void bucket_count_kernel(
    const int* __restrict__ dst, int* __restrict__ bcnt, int E, int nbuckets) {
    __shared__ int h[NBMAX];
    int t = threadIdx.x;
    for (int i = t; i < nbuckets; i += 256) h[i] = 0;
    __syncthreads();
    for (int i = blockIdx.x * 256 + t; i < E; i += gridDim.x * 256)
        atomicAdd(&h[dst[i] >> 8], 1);
    __syncthreads();
    for (int i = t; i < nbuckets; i += 256) {
        int c = h[i];
        if (c) atomicAdd(&bcnt[i], c);
    }
}

// exclusive scan of bucket counts -> bbase, and init bcur
__global__ __launch_bounds__(NBMAX) void bucket_scan_kernel(
    const int* __restrict__ bcnt, int* __restrict__ bbase, int* __restrict__ bcur, int nbuckets) {
    __shared__ int s[NBMAX];
    int t = threadIdx.x;
    int v = (t < nbuckets) ? bcnt[t] : 0;
    s[t] = v;
    __syncthreads();
    for (int off = 1; off < NBMAX; off <<= 1) {
        int tmp = (t >= off) ? s[t - off] : 0;
        __syncthreads();
        s[t] += tmp;
        __syncthreads();
    }
    if (t < nbuckets) {
        int ex = s[t] - v;
        bbase[t] = ex;
        bcur[t] = ex;
    }
}

// Pass B: group edges by bucket into ebuf (int2 = {src, dst})
__global__ __launch_bounds__(256) void bucket_fill_kernel(
    const int* __restrict__ src, const int* __restrict__ dst, int* __restrict__ bcur,
    int2* __restrict__ ebuf, int E, int nbuckets, int chunk) {
    __shared__ int h[NBMAX];
    int t = threadIdx.x;
    for (int i = t; i < nbuckets; i += 256) h[i] = 0;
    __syncthreads();
    int lo = blockIdx.x * chunk, hi = min(E, lo + chunk);
    for (int i = lo + t; i < hi; i += 256)
        atomicAdd(&h[dst[i] >> 8], 1);
    __syncthreads();
    for (int i = t; i < nbuckets; i += 256) {
        int c = h[i];
        h[i] = c ? atomicAdd(&bcur[i], c) : 0;   // h becomes block's write cursor
    }
    __syncthreads();
    for (int i = lo + t; i < hi; i += 256) {
        int d = dst[i];
        int p = atomicAdd(&h[d >> 8], 1);        // LDS atomic
        ebuf[p] = make_int2(src[i], d);
    }
}

// Pass C: one block per bucket -> per-node CSR via LDS hist/scan/scatter
__global__ __launch_bounds__(256) void csr_build_kernel(
    const int* __restrict__ bbase, const int* __restrict__ bcnt,
    const int2* __restrict__ ebuf, int* __restrict__ row_start,
    int* __restrict__ col, int N, int E) {
    __shared__ int hist[256];
    __shared__ int sc[256];
    int b = blockIdx.x, t = threadIdx.x;
    int beg = bbase[b], cnt = bcnt[b];
    hist[t] = 0;
    __syncthreads();
    for (int i = t; i < cnt; i += 256)
        atomicAdd(&hist[ebuf[beg + i].y & 255], 1);
    __syncthreads();
    int v = hist[t];
    sc[t] = v;
    __syncthreads();
    for (int off = 1; off < 256; off <<= 1) {
        int tmp = (t >= off) ? sc[t - off] : 0;
        __syncthreads();
        sc[t] += tmp;
        __syncthreads();
    }
    int ex = sc[t] - v;                 // exclusive prefix within bucket
    int node = b * 256 + t;
    if (node < N) row_start[node] = beg + ex;
    hist[t] = ex;                       // becomes per-node cursor
    __syncthreads();
    for (int i = t; i < cnt; i += 256) {
        int2 e = ebuf[beg + i];
        int p = atomicAdd(&hist[e.y & 255], 1);   // LDS atomic
        col[beg + p] = e.x;
    }
    if (b == 0 && t == 0) row_start[N] = E;
}

// ---------------- weight prep: f32 (K x 128) -> f16 transposed [n][k] ----------------
// slot 0: w2_0 ; slots 1..4: ws2[0..3] ; slots 5..8: ws1[0..3]
__global__ void prep_w_kernel(const float* __restrict__ w20, const float* __restrict__ ws1,
                              const float* __restrict__ ws2, _Float16* __restrict__ wt) {
    int i = blockIdx.x * blockDim.x + threadIdx.x;
    if (i >= 9 * 16384) return;
    int w = i >> 14, r = i & 16383;
    int n = r >> 7, k = r & 127;
    const float* src = (w == 0) ? w20 : (w <= 4 ? ws2 + (size_t)(w - 1) * 16384
                                                : ws1 + (size_t)(w - 5) * 16384);
    wt[(size_t)w * 16384 + n * H + k] = (_Float16)src[k * H + n];
}

// pad x (N x 9 f32) -> xp (N x 16 f32, zero-padded)
__global__ void prep_x_kernel(const float* __restrict__ x, float* __restrict__ xp, int N) {
    int i = blockIdx.x * blockDim.x + threadIdx.x;
    if (i >= N * 16) return;
    int n = i >> 4, c = i & 15;
    xp[i] = (c < F) ? x[n * F + c] : 0.f;
}

// ---------------- layer 0: gather (padded F=16) + fused 9->128 linear + ReLU ----------------
// 16 lanes per node (1 float each), 4 nodes per wave, 4 waves per block => 16 nodes/block.
__global__ __launch_bounds__(256) void gather0_kernel(
    const float* __restrict__ xp, const int* __restrict__ row_start,
    const int* __restrict__ col, const float* __restrict__ w1,
    const float* __restrict__ b1, _Float16* __restrict__ zbuf, int N) {
    int t = threadIdx.x;
    int wave = t >> 6, lane = t & 63;
    int sub = lane >> 4, li = lane & 15;
    int node = (blockIdx.x * 4 + wave) * 4 + sub;
    bool valid = node < N;
    float acc = 0.f;
    if (valid) {
        acc = xp[(size_t)node * 16 + li];
        int beg = row_start[node], end = row_start[node + 1];
        int j = beg;
        for (; j + 3 < end; j += 4) {
            int v0 = col[j], v1 = col[j + 1], v2 = col[j + 2], v3 = col[j + 3];
            float x0 = xp[(size_t)v0 * 16 + li];
            float x1 = xp[(size_t)v1 * 16 + li];
            float x2 = xp[(size_t)v2 * 16 + li];
            float x3 = xp[(size_t)v3 * 16 + li];
            acc += (x0 + x1) + (x2 + x3);
        }
        for (; j < end; ++j) acc += xp[(size_t)col[j] * 16 + li];
    }
    // node sub's features k=0..8 live in lanes sub*16+k. Each lane computes 8 channels.
    float y[8];
    {
        f32x4 b0 = ((const f32x4*)b1)[li * 2], b1v = ((const f32x4*)b1)[li * 2 + 1];
#pragma unroll
        for (int u = 0; u < 4; ++u) { y[u] = b0[u]; y[4 + u] = b1v[u]; }
    }
#pragma unroll
    for (int k = 0; k < F; ++k) {
        float zk = __shfl(acc, (lane & 48) | k, 64);
        f32x4 w0 = ((const f32x4*)(w1 + k * H))[li * 2];
        f32x4 w1v = ((const f32x4*)(w1 + k * H))[li * 2 + 1];
#pragma unroll
        for (int u = 0; u < 4; ++u) { y[u] += zk * w0[u]; y[4 + u] += zk * w1v[u]; }
    }
    if (valid) {
        f16x8 hz;
#pragma unroll
        for (int u = 0; u < 8; ++u) hz[u] = (_Float16)fmaxf(y[u], 0.f);
        ((f16x8*)zbuf)[(size_t)node * 16 + li] = hz;
    }
}

// ---------------- layers 1..4: gather with fused BN(prev)+ReLU on load ----------------
// 16 lanes per node (f16x8 = 16B slice each), 4 nodes per wave, 8-deep unroll.
__global__ __launch_bounds__(256) void gather_kernel(
    const _Float16* __restrict__ y, const float* __restrict__ scale,
    const float* __restrict__ shift, const int* __restrict__ row_start,
    const int* __restrict__ col, _Float16* __restrict__ zbuf, int N) {
    int t = threadIdx.x;
    int wave = t >> 6, lane = t & 63;
    int sub = lane >> 4, li = lane & 15;
    int node = (blockIdx.x * 4 + wave) * 4 + sub;
    if (node >= N) return;
    float sc[8], sh[8];
    {
        f32x4 s0 = ((const f32x4*)scale)[li * 2], s1 = ((const f32x4*)scale)[li * 2 + 1];
        f32x4 h0 = ((const f32x4*)shift)[li * 2], h1 = ((const f32x4*)shift)[li * 2 + 1];
#pragma unroll
        for (int u = 0; u < 4; ++u) { sc[u] = s0[u]; sc[4 + u] = s1[u]; sh[u] = h0[u]; sh[4 + u] = h1[u]; }
    }
    const f16x8* yp = (const f16x8*)y;
    float a[8];
    {
        f16x8 h = yp[(size_t)node * 16 + li];
#pragma unroll
        for (int u = 0; u < 8; ++u) a[u] = fmaxf((float)h[u] * sc[u] + sh[u], 0.f);
    }
    int beg = row_start[node], end = row_start[node + 1];
    int j = beg;
    for (; j + 7 < end; j += 8) {
        int v0 = col[j], v1 = col[j + 1], v2 = col[j + 2], v3 = col[j + 3];
        int v4 = col[j + 4], v5 = col[j + 5], v6 = col[j + 6], v7 = col[j + 7];
        f16x8 h0 = yp[(size_t)v0 * 16 + li];
        f16x8 h1 = yp[(size_t)v1 * 16 + li];
        f16x8 h2 = yp[(size_t)v2 * 16 + li];
        f16x8 h3 = yp[(size_t)v3 * 16 + li];
        f16x8 h4 = yp[(size_t)v4 * 16 + li];
        f16x8 h5 = yp[(size_t)v5 * 16 + li];
        f16x8 h6 = yp[(size_t)v6 * 16 + li];
        f16x8 h7 = yp[(size_t)v7 * 16 + li];
#pragma unroll
        for (int u = 0; u < 8; ++u) {
            float p0 = fmaxf((float)h0[u] * sc[u] + sh[u], 0.f);
            float p1 = fmaxf((float)h1[u] * sc[u] + sh[u], 0.f);
            float p2 = fmaxf((float)h2[u] * sc[u] + sh[u], 0.f);
            float p3 = fmaxf((float)h3[u] * sc[u] + sh[u], 0.f);
            float p4 = fmaxf((float)h4[u] * sc[u] + sh[u], 0.f);
            float p5 = fmaxf((float)h5[u] * sc[u] + sh[u], 0.f);
            float p6 = fmaxf((float)h6[u] * sc[u] + sh[u], 0.f);
            float p7 = fmaxf((float)h7[u] * sc[u] + sh[u], 0.f);
            a[u] += ((p0 + p1) + (p2 + p3)) + ((p4 + p5) + (p6 + p7));
        }
    }
    for (; j + 3 < end; j += 4) {
        int v0 = col[j], v1 = col[j + 1], v2 = col[j + 2], v3 = col[j + 3];
        f16x8 h0 = yp[(size_t)v0 * 16 + li];
        f16x8 h1 = yp[(size_t)v1 * 16 + li];
        f16x8 h2 = yp[(size_t)v2 * 16 + li];
        f16x8 h3 = yp[(size_t)v3 * 16 + li];
#pragma unroll
        for (int u = 0; u < 8; ++u) {
            float p0 = fmaxf((float)h0[u] * sc[u] + sh[u], 0.f);
            float p1 = fmaxf((float)h1[u] * sc[u] + sh[u], 0.f);
            float p2 = fmaxf((float)h2[u] * sc[u] + sh[u], 0.f);
            float p3 = fmaxf((float)h3[u] * sc[u] + sh[u], 0.f);
            a[u] += (p0 + p1) + (p2 + p3);
        }
    }
    for (; j < end; ++j) {
        int v = col[j];
        f16x8 h = yp[(size_t)v * 16 + li];
#pragma unroll
        for (int u = 0; u < 8; ++u) a[u] += fmaxf((float)h[u] * sc[u] + sh[u], 0.f);
    }
    f16x8 hz;
#pragma unroll
    for (int u = 0; u < 8; ++u) hz[u] = (_Float16)a[u];
    ((f16x8*)zbuf)[(size_t)node * 16 + li] = hz;
}

// ---------------- fused MLP (MFMA f16) + BN partial stats ----------------
// FULL=true : Y = relu(Z@W1+b1)@W2 + b2    FULL=false : Y = Z@W2 + b2
// ONE wave per block; wave owns 64 nodes (4 M-tiles of 16). Each B-frag load
// feeds 4 MFMAs -> 4x less weight traffic than 16-node waves. No __syncthreads.
template <bool FULL>
__global__ __launch_bounds__(64, 2) void mlp_kernel(
    const _Float16* __restrict__ zbuf, const _Float16* __restrict__ w1t,
    const float* __restrict__ b1, const _Float16* __restrict__ w2t,
    const float* __restrict__ b2, _Float16* __restrict__ ybuf,
    float* __restrict__ stats, int N) {
    const int lane = threadIdx.x & 63;
    const int li = lane & 15, kg = lane >> 4;
    const int node0 = blockIdx.x * 64;

    const f32x4 z4 = {0.f, 0.f, 0.f, 0.f};
    f32x4 acc2[4][8];
#pragma unroll
    for (int m = 0; m < 4; ++m)
#pragma unroll
        for (int tt = 0; tt < 8; ++tt) acc2[m][tt] = z4;

    if constexpr (FULL) {
        __shared__ _Float16 y1_lds[64 * 136];   // 64 nodes x 128 ch, stride 136
        f32x4 acc1[4][8];
#pragma unroll
        for (int m = 0; m < 4; ++m)
#pragma unroll
            for (int tt = 0; tt < 8; ++tt) acc1[m][tt] = z4;
#pragma unroll
        for (int ks = 0; ks < 4; ++ks) {
            f16x8 a[4];
#pragma unroll
            for (int m = 0; m < 4; ++m)
                a[m] = *(const f16x8*)(zbuf + (size_t)(node0 + m * 16 + li) * H + ks * 32 + kg * 8);
#pragma unroll
            for (int tt = 0; tt < 8; ++tt) {
                f16x8 b = *(const f16x8*)(w1t + (size_t)(tt * 16 + li) * H + ks * 32 + kg * 8);
#pragma unroll
                for (int m = 0; m < 4; ++m)
                    acc1[m][tt] = __builtin_amdgcn_mfma_f32_16x16x32_f16(a[m], b, acc1[m][tt], 0, 0, 0);
            }
        }
        // bias + ReLU -> y1 LDS (same-wave RAW, no barrier needed)
#pragma unroll
        for (int tt = 0; tt < 8; ++tt) {
            int c = tt * 16 + li;
            float bb = b1[c];
#pragma unroll
            for (int m = 0; m < 4; ++m)
#pragma unroll
                for (int r = 0; r < 4; ++r) {
                    float v = fmaxf(acc1[m][tt][r] + bb, 0.f);   // D row = 4*kg + r
                    y1_lds[(m * 16 + kg * 4 + r) * 136 + c] = (_Float16)v;
                }
        }
#pragma unroll
        for (int ks = 0; ks < 4; ++ks) {
            f16x8 a[4];
#pragma unroll
            for (int m = 0; m < 4; ++m)
                a[m] = *(const f16x8*)(y1_lds + (m * 16 + li) * 136 + ks * 32 + kg * 8);
#pragma unroll
            for (int tt = 0; tt < 8; ++tt) {
                f16x8 b = *(const f16x8*)(w2t + (size_t)(tt * 16 + li) * H + ks * 32 + kg * 8);
#pragma unroll
                for (int m = 0; m < 4; ++m)
                    acc2[m][tt] = __builtin_amdgcn_mfma_f32_16x16x32_f16(a[m], b, acc2[m][tt], 0, 0, 0);
            }
        }
    } else {
#pragma unroll
        for (int ks = 0; ks < 4; ++ks) {
            f16x8 a[4];
#pragma unroll
            for (int m = 0; m < 4; ++m)
                a[m] = *(const f16x8*)(zbuf + (size_t)(node0 + m * 16 + li) * H + ks * 32 + kg * 8);
#pragma unroll
            for (int tt = 0; tt < 8; ++tt) {
                f16x8 b = *(const f16x8*)(w2t + (size_t)(tt * 16 + li) * H + ks * 32 + kg * 8);
#pragma unroll
                for (int m = 0; m < 4; ++m)
                    acc2[m][tt] = __builtin_amdgcn_mfma_f32_16x16x32_f16(a[m], b, acc2[m][tt], 0, 0, 0);
            }
        }
    }

    // epilogue: bias, store f16 Y, per-channel stats (shfl-reduce -> global atomic)
#pragma unroll
    for (int tt = 0; tt < 8; ++tt) {
        int c = tt * 16 + li;
        float bb = b2[c];
        float s1 = 0.f, s2 = 0.f;
#pragma unroll
        for (int m = 0; m < 4; ++m)
#pragma unroll
            for (int r = 0; r < 4; ++r) {
                int node = node0 + m * 16 + kg * 4 + r;
                float v = acc2[m][tt][r] + bb;
                if (node < N) {
                    ybuf[(size_t)node * H + c] = (_Float16)v;
                    s1 += v; s2 += v * v;
                }
            }
        s1 += __shfl_xor(s1, 16, 64); s2 += __shfl_xor(s2, 16, 64);
        s1 += __shfl_xor(s1, 32, 64); s2 += __shfl_xor(s2, 32, 64);
        if (kg == 0) {
            atomicAdd(&stats[c], s1);
            atomicAdd(&stats[128 + c], s2);
        }
    }
}

__global__ void stats_final_kernel(const float* __restrict__ stats, const float* __restrict__ gamma,
                                   const float* __restrict__ beta, float* __restrict__ scale,
                                   float* __restrict__ shift, int N) {
    int c = threadIdx.x;   // 128 threads
    float invN = 1.f / (float)N;
    float mean = stats[c] * invN;
    float var = stats[128 + c] * invN - mean * mean;
    float inv = rsqrtf(var + BN_EPS);
    float sc = gamma[c] * inv;
    scale[c] = sc;
    shift[c] = beta[c] - mean * sc;
}

// vectorized: N*H/4 float4 stores for h, then N scalar stores for batch passthrough
__global__ void finalize_kernel(const _Float16* __restrict__ ybuf, const float* __restrict__ scale,
                                const float* __restrict__ shift, const int* __restrict__ batch,
                                float* __restrict__ out, int N) {
    int nh4 = N * (H / 4);
    int total = nh4 + N;
    for (int i = blockIdx.x * blockDim.x + threadIdx.x; i < total; i += gridDim.x * blockDim.x) {
        if (i < nh4) {
            f16x4 h = ((const f16x4*)ybuf)[i];
            int c = (i & 31) * 4;
            f32x4 sc = *(const f32x4*)(scale + c);
            f32x4 sh = *(const f32x4*)(shift + c);
            f32x4 o;
#pragma unroll
            for (int u = 0; u < 4; ++u) o[u] = fmaxf((float)h[u] * sc[u] + sh[u], 0.f);
            ((f32x4*)out)[i] = o;
        } else {
            int b = i - nh4;
            out[(size_t)N * H + b] = (float)batch[b];
        }
    }
}

// ---------------- launch ----------------

extern "C" void kernel_launch(void* const* d_in, const int* in_sizes, int n_in,
                              void* d_out, int out_size, void* d_ws, size_t ws_size,
                              hipStream_t stream) {
    const float* x      = (const float*)d_in[0];
    const int*   eidx   = (const int*)d_in[1];
    const int*   batch  = (const int*)d_in[2];
    const float* w1_0   = (const float*)d_in[3];
    const float* b1_0   = (const float*)d_in[4];
    const float* w2_0   = (const float*)d_in[5];
    const float* b2_0   = (const float*)d_in[6];
    const float* gamma0 = (const float*)d_in[7];
    const float* beta0  = (const float*)d_in[8];
    const float* ws1    = (const float*)d_in[9];
    const float* bs1    = (const float*)d_in[10];
    const float* ws2    = (const float*)d_in[11];
    const float* bs2    = (const float*)d_in[12];
    const float* gammas = (const float*)d_in[13];
    const float* betas  = (const float*)d_in[14];

    const int N = in_sizes[2];
    const int E = in_sizes[1] / 2;
    const int Npad = (N + 63) & ~63;
    const int* srcv = eidx;          // edge_index[0]
    const int* dstv = eidx + E;      // edge_index[1]

    char* p = (char*)d_ws;
    size_t o = 0;
    auto alloc = [&](size_t bytes) {
        void* r = p + o;
        o = (o + bytes + 255) & ~(size_t)255;
        return r;
    };
    int* col        = (int*)alloc((size_t)E * 4);
    int* row_start  = (int*)alloc((size_t)(N + 1) * 4);
    int* bcnt       = (int*)alloc(NBMAX * 4);
    int* bbase      = (int*)alloc(NBMAX * 4);
    int* bcur       = (int*)alloc(NBMAX * 4);
    _Float16* wt    = (_Float16*)alloc((size_t)9 * 16384 * 2);
    float* stats    = (float*)alloc(256 * 4);
    float* scale    = (float*)alloc(128 * 4);
    float* shift    = (float*)alloc(128 * 4);
    float* xp       = (float*)alloc((size_t)N * 16 * 4);
    _Float16* zbuf  = (_Float16*)alloc((size_t)Npad * H * 2);
    _Float16* ybuf  = (_Float16*)alloc((size_t)Npad * H * 2);
    int2* ebuf      = (int2*)zbuf;   // alias: ebuf (E*8B) dead before zbuf first written
    (void)ws_size; (void)n_in; (void)out_size;

    const int nbuckets = (N + 255) >> 8;
    const int mblocks = Npad / 64;       // one 64-node wave per block
    const int gblocks = (N + 15) / 16;   // 16 nodes per block
    const int fchunk = (E + 255) / 256;  // edges per bucket_fill block

    // bucketed CSR build
    hipMemsetAsync(bcnt, 0, NBMAX * 4, stream);
    bucket_count_kernel<<<256, 256, 0, stream>>>(dstv, bcnt, E, nbuckets);
    bucket_scan_kernel<<<1, NBMAX, 0, stream>>>(bcnt, bbase, bcur, nbuckets);
    bucket_fill_kernel<<<256, 256, 0, stream>>>(srcv, dstv, bcur, ebuf, E, nbuckets, fchunk);
    csr_build_kernel<<<nbuckets, 256, 0, stream>>>(bbase, bcnt, ebuf, row_start, col, N, E);

    prep_w_kernel<<<(9 * 16384 + 255) / 256, 256, 0, stream>>>(w2_0, ws1, ws2, wt);
    prep_x_kernel<<<(N * 16 + 255) / 256, 256, 0, stream>>>(x, xp, N);

    // layer 0: gather over xp (padded F=16) with fused 9->128 linear; then half-MLP + stats
    gather0_kernel<<<gblocks, 256, 0, stream>>>(xp, row_start, col, w1_0, b1_0, zbuf, N);
    hipMemsetAsync(stats, 0, 256 * 4, stream);
    mlp_kernel<false><<<mblocks, 64, 0, stream>>>(zbuf, nullptr, nullptr, wt, b2_0, ybuf, stats, N);
    stats_final_kernel<<<1, 128, 0, stream>>>(stats, gamma0, beta0, scale, shift, N);

    // layers 1..4
    for (int l = 1; l <= 4; ++l) {
        gather_kernel<<<gblocks, 256, 0, stream>>>(ybuf, scale, shift, row_start, col, zbuf, N);
        hipMemsetAsync(stats, 0, 256 * 4, stream);
        mlp_kernel<true><<<mblocks, 64, 0, stream>>>(
            zbuf, wt + (size_t)(4 + l) * 16384, bs1 + (size_t)(l - 1) * H,
            wt + (size_t)l * 16384, bs2 + (size_t)(l - 1) * H, ybuf, stats, N);
        stats_final_kernel<<<1, 128, 0, stream>>>(stats, gammas + (size_t)(l - 1) * H,
                                                  betas + (size_t)(l - 1) * H, scale, shift, N);
    }

    finalize_kernel<<<2048, 256, 0, stream>>>(ybuf, scale, shift, batch, (float*)d_out, N);
}

// Round 5
// 855.081 us; speedup vs baseline: 1.0799x; 1.0799x over previous
//
#include <hip/hip_runtime.h>

constexpr int H = 128;
constexpr int F = 9;
constexpr float BN_EPS = 1e-5f;
constexpr int NBMAX = 512;      // max dst buckets (256 nodes each, N <= 131072)

typedef _Float16 f16x8 __attribute__((ext_vector_type(8)));
typedef _Float16 f16x4 __attribute__((ext_vector_type(4)));
typedef float    f32x4 __attribute__((ext_vector_type(4)));

// ---------------- bucketed CSR build (no per-node global atomics) ----------------

__global__ __launch_bounds__(256) void bucket_count_kernel(
    const int* __restrict__ dst, int* __restrict__ bcnt, int E, int nbuckets) {
    __shared__ int h[NBMAX];
    int t = threadIdx.x;
    for (int i = t; i < nbuckets; i += 256) h[i] = 0;
    __syncthreads();
    for (int i = blockIdx.x * 256 + t; i < E; i += gridDim.x * 256)
        atomicAdd(&h[dst[i] >> 8], 1);
    __syncthreads();
    for (int i = t; i < nbuckets; i += 256) {
        int c = h[i];
        if (c) atomicAdd(&bcnt[i], c);
    }
}

__global__ __launch_bounds__(NBMAX) void bucket_scan_kernel(
    const int* __restrict__ bcnt, int* __restrict__ bbase, int* __restrict__ bcur, int nbuckets) {
    __shared__ int s[NBMAX];
    int t = threadIdx.x;
    int v = (t < nbuckets) ? bcnt[t] : 0;
    s[t] = v;
    __syncthreads();
    for (int off = 1; off < NBMAX; off <<= 1) {
        int tmp = (t >= off) ? s[t - off] : 0;
        __syncthreads();
        s[t] += tmp;
        __syncthreads();
    }
    if (t < nbuckets) {
        int ex = s[t] - v;
        bbase[t] = ex;
        bcur[t] = ex;
    }
}

__global__ __launch_bounds__(256) void bucket_fill_kernel(
    const int* __restrict__ src, const int* __restrict__ dst, int* __restrict__ bcur,
    int2* __restrict__ ebuf, int E, int nbuckets, int chunk) {
    __shared__ int h[NBMAX];
    int t = threadIdx.x;
    for (int i = t; i < nbuckets; i += 256) h[i] = 0;
    __syncthreads();
    int lo = blockIdx.x * chunk, hi = min(E, lo + chunk);
    for (int i = lo + t; i < hi; i += 256)
        atomicAdd(&h[dst[i] >> 8], 1);
    __syncthreads();
    for (int i = t; i < nbuckets; i += 256) {
        int c = h[i];
        h[i] = c ? atomicAdd(&bcur[i], c) : 0;   // h becomes block's write cursor
    }
    __syncthreads();
    for (int i = lo + t; i < hi; i += 256) {
        int d = dst[i];
        int p = atomicAdd(&h[d >> 8], 1);        // LDS atomic
        ebuf[p] = make_int2(src[i], d);
    }
}

__global__ __launch_bounds__(256) void csr_build_kernel(
    const int* __restrict__ bbase, const int* __restrict__ bcnt,
    const int2* __restrict__ ebuf, int* __restrict__ row_start,
    int* __restrict__ col, int N, int E) {
    __shared__ int hist[256];
    __shared__ int sc[256];
    int b = blockIdx.x, t = threadIdx.x;
    int beg = bbase[b], cnt = bcnt[b];
    hist[t] = 0;
    __syncthreads();
    for (int i = t; i < cnt; i += 256)
        atomicAdd(&hist[ebuf[beg + i].y & 255], 1);
    __syncthreads();
    int v = hist[t];
    sc[t] = v;
    __syncthreads();
    for (int off = 1; off < 256; off <<= 1) {
        int tmp = (t >= off) ? sc[t - off] : 0;
        __syncthreads();
        sc[t] += tmp;
        __syncthreads();
    }
    int ex = sc[t] - v;                 // exclusive prefix within bucket
    int node = b * 256 + t;
    if (node < N) row_start[node] = beg + ex;
    hist[t] = ex;                       // becomes per-node cursor
    __syncthreads();
    for (int i = t; i < cnt; i += 256) {
        int2 e = ebuf[beg + i];
        int p = atomicAdd(&hist[e.y & 255], 1);   // LDS atomic
        col[beg + p] = e.x;
    }
    if (b == 0 && t == 0) row_start[N] = E;
}

// ---------------- weight prep: f32 (K x 128) -> f16 in MFMA-FRAGMENT order ----------------
// slot 0: w2_0 ; slots 1..4: ws2[0..3] ; slots 5..8: ws1[0..3]
// layout: wf[w][((tt*4+ks)*64 + lane)*8 + e] = src[k*128 + n],
//   n = tt*16 + (lane&15), k = ks*32 + (lane>>4)*8 + e
// -> in-kernel B-frag read = contiguous 1024B per wave = conflict-free ds_read_b128.
__global__ void prep_w_kernel(const float* __restrict__ w20, const float* __restrict__ ws1,
                              const float* __restrict__ ws2, _Float16* __restrict__ wf) {
    int i = blockIdx.x * blockDim.x + threadIdx.x;
    if (i >= 9 * 16384) return;
    int w = i >> 14, r = i & 16383;
    int tt = r >> 11, ks = (r >> 9) & 3, lane = (r >> 3) & 63, e = r & 7;
    int n = tt * 16 + (lane & 15);
    int k = ks * 32 + (lane >> 4) * 8 + e;
    const float* src = (w == 0) ? w20 : (w <= 4 ? ws2 + (size_t)(w - 1) * 16384
                                                : ws1 + (size_t)(w - 5) * 16384);
    wf[i] = (_Float16)src[k * H + n];
}

// pad x (N x 9 f32) -> xp (N x 16 f32, zero-padded)
__global__ void prep_x_kernel(const float* __restrict__ x, float* __restrict__ xp, int N) {
    int i = blockIdx.x * blockDim.x + threadIdx.x;
    if (i >= N * 16) return;
    int n = i >> 4, c = i & 15;
    xp[i] = (c < F) ? x[n * F + c] : 0.f;
}

// ---------------- layer 0: gather (padded F=16) + fused 9->128 linear + ReLU ----------------
__global__ __launch_bounds__(256) void gather0_kernel(
    const float* __restrict__ xp, const int* __restrict__ row_start,
    const int* __restrict__ col, const float* __restrict__ w1,
    const float* __restrict__ b1, _Float16* __restrict__ zbuf, int N) {
    int t = threadIdx.x;
    int wave = t >> 6, lane = t & 63;
    int sub = lane >> 4, li = lane & 15;
    int node = (blockIdx.x * 4 + wave) * 4 + sub;
    bool valid = node < N;
    float acc = 0.f;
    if (valid) {
        acc = xp[(size_t)node * 16 + li];
        int beg = row_start[node], end = row_start[node + 1];
        int j = beg;
        for (; j + 3 < end; j += 4) {
            int v0 = col[j], v1 = col[j + 1], v2 = col[j + 2], v3 = col[j + 3];
            float x0 = xp[(size_t)v0 * 16 + li];
            float x1 = xp[(size_t)v1 * 16 + li];
            float x2 = xp[(size_t)v2 * 16 + li];
            float x3 = xp[(size_t)v3 * 16 + li];
            acc += (x0 + x1) + (x2 + x3);
        }
        for (; j < end; ++j) acc += xp[(size_t)col[j] * 16 + li];
    }
    float y[8];
    {
        f32x4 b0 = ((const f32x4*)b1)[li * 2], b1v = ((const f32x4*)b1)[li * 2 + 1];
#pragma unroll
        for (int u = 0; u < 4; ++u) { y[u] = b0[u]; y[4 + u] = b1v[u]; }
    }
#pragma unroll
    for (int k = 0; k < F; ++k) {
        float zk = __shfl(acc, (lane & 48) | k, 64);
        f32x4 w0 = ((const f32x4*)(w1 + k * H))[li * 2];
        f32x4 w1v = ((const f32x4*)(w1 + k * H))[li * 2 + 1];
#pragma unroll
        for (int u = 0; u < 4; ++u) { y[u] += zk * w0[u]; y[4 + u] += zk * w1v[u]; }
    }
    if (valid) {
        f16x8 hz;
#pragma unroll
        for (int u = 0; u < 8; ++u) hz[u] = (_Float16)fmaxf(y[u], 0.f);
        ((f16x8*)zbuf)[(size_t)node * 16 + li] = hz;
    }
}

// ---------------- layers 1..4: gather with fused BN(prev)+ReLU on load ----------------
__global__ __launch_bounds__(256) void gather_kernel(
    const _Float16* __restrict__ y, const float* __restrict__ scale,
    const float* __restrict__ shift, const int* __restrict__ row_start,
    const int* __restrict__ col, _Float16* __restrict__ zbuf, int N) {
    int t = threadIdx.x;
    int wave = t >> 6, lane = t & 63;
    int sub = lane >> 4, li = lane & 15;
    int node = (blockIdx.x * 4 + wave) * 4 + sub;
    if (node >= N) return;
    float sc[8], sh[8];
    {
        f32x4 s0 = ((const f32x4*)scale)[li * 2], s1 = ((const f32x4*)scale)[li * 2 + 1];
        f32x4 h0 = ((const f32x4*)shift)[li * 2], h1 = ((const f32x4*)shift)[li * 2 + 1];
#pragma unroll
        for (int u = 0; u < 4; ++u) { sc[u] = s0[u]; sc[4 + u] = s1[u]; sh[u] = h0[u]; sh[4 + u] = h1[u]; }
    }
    const f16x8* yp = (const f16x8*)y;
    float a[8];
    {
        f16x8 h = yp[(size_t)node * 16 + li];
#pragma unroll
        for (int u = 0; u < 8; ++u) a[u] = fmaxf((float)h[u] * sc[u] + sh[u], 0.f);
    }
    int beg = row_start[node], end = row_start[node + 1];
    int j = beg;
    for (; j + 7 < end; j += 8) {
        int v0 = col[j], v1 = col[j + 1], v2 = col[j + 2], v3 = col[j + 3];
        int v4 = col[j + 4], v5 = col[j + 5], v6 = col[j + 6], v7 = col[j + 7];
        f16x8 h0 = yp[(size_t)v0 * 16 + li];
        f16x8 h1 = yp[(size_t)v1 * 16 + li];
        f16x8 h2 = yp[(size_t)v2 * 16 + li];
        f16x8 h3 = yp[(size_t)v3 * 16 + li];
        f16x8 h4 = yp[(size_t)v4 * 16 + li];
        f16x8 h5 = yp[(size_t)v5 * 16 + li];
        f16x8 h6 = yp[(size_t)v6 * 16 + li];
        f16x8 h7 = yp[(size_t)v7 * 16 + li];
#pragma unroll
        for (int u = 0; u < 8; ++u) {
            float p0 = fmaxf((float)h0[u] * sc[u] + sh[u], 0.f);
            float p1 = fmaxf((float)h1[u] * sc[u] + sh[u], 0.f);
            float p2 = fmaxf((float)h2[u] * sc[u] + sh[u], 0.f);
            float p3 = fmaxf((float)h3[u] * sc[u] + sh[u], 0.f);
            float p4 = fmaxf((float)h4[u] * sc[u] + sh[u], 0.f);
            float p5 = fmaxf((float)h5[u] * sc[u] + sh[u], 0.f);
            float p6 = fmaxf((float)h6[u] * sc[u] + sh[u], 0.f);
            float p7 = fmaxf((float)h7[u] * sc[u] + sh[u], 0.f);
            a[u] += ((p0 + p1) + (p2 + p3)) + ((p4 + p5) + (p6 + p7));
        }
    }
    for (; j + 3 < end; j += 4) {
        int v0 = col[j], v1 = col[j + 1], v2 = col[j + 2], v3 = col[j + 3];
        f16x8 h0 = yp[(size_t)v0 * 16 + li];
        f16x8 h1 = yp[(size_t)v1 * 16 + li];
        f16x8 h2 = yp[(size_t)v2 * 16 + li];
        f16x8 h3 = yp[(size_t)v3 * 16 + li];
#pragma unroll
        for (int u = 0; u < 8; ++u) {
            float p0 = fmaxf((float)h0[u] * sc[u] + sh[u], 0.f);
            float p1 = fmaxf((float)h1[u] * sc[u] + sh[u], 0.f);
            float p2 = fmaxf((float)h2[u] * sc[u] + sh[u], 0.f);
            float p3 = fmaxf((float)h3[u] * sc[u] + sh[u], 0.f);
            a[u] += (p0 + p1) + (p2 + p3);
        }
    }
    for (; j < end; ++j) {
        int v = col[j];
        f16x8 h = yp[(size_t)v * 16 + li];
#pragma unroll
        for (int u = 0; u < 8; ++u) a[u] += fmaxf((float)h[u] * sc[u] + sh[u], 0.f);
    }
    f16x8 hz;
#pragma unroll
    for (int u = 0; u < 8; ++u) hz[u] = (_Float16)a[u];
    ((f16x8*)zbuf)[(size_t)node * 16 + li] = hz;
}

// ---------------- fused MLP (MFMA f16, weights in LDS) + BN stats ----------------
// Persistent blocks: stage fragment-ordered weights into LDS ONCE, then loop over
// 128-node supertiles (8 waves x 16 nodes). Zero global loads in the MFMA loops.
template <bool FULL>
__global__ __launch_bounds__(512) void mlp_kernel(
    const _Float16* __restrict__ zbuf, const _Float16* __restrict__ w1f,
    const float* __restrict__ b1, const _Float16* __restrict__ w2f,
    const float* __restrict__ b2, _Float16* __restrict__ ybuf,
    float* __restrict__ stats, int N, int nST) {
    // FULL: [0:16384)=w1 frags, [16384:32768)=w2 frags, [32768+wave*2176)=y1 (16x136)
    __shared__ _Float16 lds[FULL ? (32768 + 8 * 16 * 136) : 16384];
    const int t = threadIdx.x;
    const int wave = t >> 6, lane = t & 63;
    const int li = lane & 15, kg = lane >> 4;

    _Float16* wl1 = lds;
    _Float16* wl2 = FULL ? (lds + 16384) : lds;

    // stage weights (coalesced 16B copies, once per block)
    if constexpr (FULL) {
        const f16x8* s1 = (const f16x8*)w1f;
        const f16x8* s2 = (const f16x8*)w2f;
        f16x8* d1 = (f16x8*)wl1;
        f16x8* d2 = (f16x8*)wl2;
        for (int i = t; i < 2048; i += 512) { d1[i] = s1[i]; d2[i] = s2[i]; }
    } else {
        const f16x8* s2 = (const f16x8*)w2f;
        f16x8* d2 = (f16x8*)wl2;
        for (int i = t; i < 2048; i += 512) d2[i] = s2[i];
    }
    __syncthreads();

    float ss1[8], ss2[8];
#pragma unroll
    for (int tt = 0; tt < 8; ++tt) { ss1[tt] = 0.f; ss2[tt] = 0.f; }

    const f32x4 z4 = {0.f, 0.f, 0.f, 0.f};
    const f16x8* wf1 = (const f16x8*)wl1;
    const f16x8* wf2 = (const f16x8*)wl2;

    for (int st = blockIdx.x; st < nST; st += gridDim.x) {
        const int node0 = st * 128 + wave * 16;
        f32x4 acc2[8];

        if constexpr (FULL) {
            _Float16* y1 = lds + 32768 + wave * (16 * 136);
            f32x4 acc1[8];
#pragma unroll
            for (int tt = 0; tt < 8; ++tt) acc1[tt] = z4;
            f16x8 a[4];
#pragma unroll
            for (int ks = 0; ks < 4; ++ks)
                a[ks] = *(const f16x8*)(zbuf + (size_t)(node0 + li) * H + ks * 32 + kg * 8);
#pragma unroll
            for (int ks = 0; ks < 4; ++ks)
#pragma unroll
                for (int tt = 0; tt < 8; ++tt)
                    acc1[tt] = __builtin_amdgcn_mfma_f32_16x16x32_f16(
                        a[ks], wf1[(tt * 4 + ks) * 64 + lane], acc1[tt], 0, 0, 0);
            // bias + ReLU -> y1 LDS (same-wave RAW only)
#pragma unroll
            for (int tt = 0; tt < 8; ++tt) {
                int c = tt * 16 + li;
                float bb = b1[c];
#pragma unroll
                for (int r = 0; r < 4; ++r)
                    y1[(kg * 4 + r) * 136 + c] = (_Float16)fmaxf(acc1[tt][r] + bb, 0.f);
            }
#pragma unroll
            for (int tt = 0; tt < 8; ++tt) acc2[tt] = z4;
            f16x8 a2[4];
#pragma unroll
            for (int ks = 0; ks < 4; ++ks)
                a2[ks] = *(const f16x8*)(y1 + li * 136 + ks * 32 + kg * 8);
#pragma unroll
            for (int ks = 0; ks < 4; ++ks)
#pragma unroll
                for (int tt = 0; tt < 8; ++tt)
                    acc2[tt] = __builtin_amdgcn_mfma_f32_16x16x32_f16(
                        a2[ks], wf2[(tt * 4 + ks) * 64 + lane], acc2[tt], 0, 0, 0);
        } else {
#pragma unroll
            for (int tt = 0; tt < 8; ++tt) acc2[tt] = z4;
            f16x8 a[4];
#pragma unroll
            for (int ks = 0; ks < 4; ++ks)
                a[ks] = *(const f16x8*)(zbuf + (size_t)(node0 + li) * H + ks * 32 + kg * 8);
#pragma unroll
            for (int ks = 0; ks < 4; ++ks)
#pragma unroll
                for (int tt = 0; tt < 8; ++tt)
                    acc2[tt] = __builtin_amdgcn_mfma_f32_16x16x32_f16(
                        a[ks], wf2[(tt * 4 + ks) * 64 + lane], acc2[tt], 0, 0, 0);
        }

        // epilogue: bias, store f16 Y, accumulate stats in registers
#pragma unroll
        for (int tt = 0; tt < 8; ++tt) {
            int c = tt * 16 + li;
            float bb = b2[c];
#pragma unroll
            for (int r = 0; r < 4; ++r) {
                int node = node0 + kg * 4 + r;
                float v = acc2[tt][r] + bb;
                if (node < N) {
                    ybuf[(size_t)node * H + c] = (_Float16)v;
                    ss1[tt] += v; ss2[tt] += v * v;
                }
            }
        }
    }

    // final stats: shfl-reduce kg groups, one atomic pass per block
#pragma unroll
    for (int tt = 0; tt < 8; ++tt) {
        float s1 = ss1[tt], s2 = ss2[tt];
        s1 += __shfl_xor(s1, 16, 64); s2 += __shfl_xor(s2, 16, 64);
        s1 += __shfl_xor(s1, 32, 64); s2 += __shfl_xor(s2, 32, 64);
        if (kg == 0) {
            int c = tt * 16 + li;
            atomicAdd(&stats[c], s1);
            atomicAdd(&stats[128 + c], s2);
        }
    }
}

__global__ void stats_final_kernel(const float* __restrict__ stats, const float* __restrict__ gamma,
                                   const float* __restrict__ beta, float* __restrict__ scale,
                                   float* __restrict__ shift, int N) {
    int c = threadIdx.x;   // 128 threads
    float invN = 1.f / (float)N;
    float mean = stats[c] * invN;
    float var = stats[128 + c] * invN - mean * mean;
    float inv = rsqrtf(var + BN_EPS);
    float sc = gamma[c] * inv;
    scale[c] = sc;
    shift[c] = beta[c] - mean * sc;
}

__global__ void finalize_kernel(const _Float16* __restrict__ ybuf, const float* __restrict__ scale,
                                const float* __restrict__ shift, const int* __restrict__ batch,
                                float* __restrict__ out, int N) {
    int nh4 = N * (H / 4);
    int total = nh4 + N;
    for (int i = blockIdx.x * blockDim.x + threadIdx.x; i < total; i += gridDim.x * blockDim.x) {
        if (i < nh4) {
            f16x4 h = ((const f16x4*)ybuf)[i];
            int c = (i & 31) * 4;
            f32x4 sc = *(const f32x4*)(scale + c);
            f32x4 sh = *(const f32x4*)(shift + c);
            f32x4 o;
#pragma unroll
            for (int u = 0; u < 4; ++u) o[u] = fmaxf((float)h[u] * sc[u] + sh[u], 0.f);
            ((f32x4*)out)[i] = o;
        } else {
            int b = i - nh4;
            out[(size_t)N * H + b] = (float)batch[b];
        }
    }
}

// ---------------- launch ----------------

extern "C" void kernel_launch(void* const* d_in, const int* in_sizes, int n_in,
                              void* d_out, int out_size, void* d_ws, size_t ws_size,
                              hipStream_t stream) {
    const float* x      = (const float*)d_in[0];
    const int*   eidx   = (const int*)d_in[1];
    const int*   batch  = (const int*)d_in[2];
    const float* w1_0   = (const float*)d_in[3];
    const float* b1_0   = (const float*)d_in[4];
    const float* w2_0   = (const float*)d_in[5];
    const float* b2_0   = (const float*)d_in[6];
    const float* gamma0 = (const float*)d_in[7];
    const float* beta0  = (const float*)d_in[8];
    const float* ws1    = (const float*)d_in[9];
    const float* bs1    = (const float*)d_in[10];
    const float* ws2    = (const float*)d_in[11];
    const float* bs2    = (const float*)d_in[12];
    const float* gammas = (const float*)d_in[13];
    const float* betas  = (const float*)d_in[14];

    const int N = in_sizes[2];
    const int E = in_sizes[1] / 2;
    const int Npad2 = (N + 127) & ~127;   // supertile-aligned
    const int* srcv = eidx;          // edge_index[0]
    const int* dstv = eidx + E;      // edge_index[1]

    char* p = (char*)d_ws;
    size_t o = 0;
    auto alloc = [&](size_t bytes) {
        void* r = p + o;
        o = (o + bytes + 255) & ~(size_t)255;
        return r;
    };
    int* col        = (int*)alloc((size_t)E * 4);
    int* row_start  = (int*)alloc((size_t)(N + 1) * 4);
    int* bcnt       = (int*)alloc(NBMAX * 4);
    int* bbase      = (int*)alloc(NBMAX * 4);
    int* bcur       = (int*)alloc(NBMAX * 4);
    _Float16* wt    = (_Float16*)alloc((size_t)9 * 16384 * 2);
    float* stats    = (float*)alloc(256 * 4);
    float* scale    = (float*)alloc(128 * 4);
    float* shift    = (float*)alloc(128 * 4);
    float* xp       = (float*)alloc((size_t)N * 16 * 4);
    _Float16* zbuf  = (_Float16*)alloc((size_t)Npad2 * H * 2);
    _Float16* ybuf  = (_Float16*)alloc((size_t)Npad2 * H * 2);
    int2* ebuf      = (int2*)zbuf;   // alias: ebuf (E*8B) dead before zbuf first written
    (void)ws_size; (void)n_in; (void)out_size;

    const int nbuckets = (N + 255) >> 8;
    const int nST = Npad2 / 128;         // 128-node supertiles
    const int gblocks = (N + 15) / 16;   // 16 nodes per block
    const int fchunk = (E + 255) / 256;  // edges per bucket_fill block

    // bucketed CSR build
    hipMemsetAsync(bcnt, 0, NBMAX * 4, stream);
    bucket_count_kernel<<<256, 256, 0, stream>>>(dstv, bcnt, E, nbuckets);
    bucket_scan_kernel<<<1, NBMAX, 0, stream>>>(bcnt, bbase, bcur, nbuckets);
    bucket_fill_kernel<<<256, 256, 0, stream>>>(srcv, dstv, bcur, ebuf, E, nbuckets, fchunk);
    csr_build_kernel<<<nbuckets, 256, 0, stream>>>(bbase, bcnt, ebuf, row_start, col, N, E);

    prep_w_kernel<<<(9 * 16384 + 255) / 256, 256, 0, stream>>>(w2_0, ws1, ws2, wt);
    prep_x_kernel<<<(N * 16 + 255) / 256, 256, 0, stream>>>(x, xp, N);

    // layer 0: gather over xp with fused 9->128 linear; then half-MLP + stats
    gather0_kernel<<<gblocks, 256, 0, stream>>>(xp, row_start, col, w1_0, b1_0, zbuf, N);
    hipMemsetAsync(stats, 0, 256 * 4, stream);
    mlp_kernel<false><<<512, 512, 0, stream>>>(zbuf, nullptr, nullptr, wt, b2_0, ybuf, stats, N, nST);
    stats_final_kernel<<<1, 128, 0, stream>>>(stats, gamma0, beta0, scale, shift, N);

    // layers 1..4
    for (int l = 1; l <= 4; ++l) {
        gather_kernel<<<gblocks, 256, 0, stream>>>(ybuf, scale, shift, row_start, col, zbuf, N);
        hipMemsetAsync(stats, 0, 256 * 4, stream);
        mlp_kernel<true><<<256, 512, 0, stream>>>(
            zbuf, wt + (size_t)(4 + l) * 16384, bs1 + (size_t)(l - 1) * H,
            wt + (size_t)l * 16384, bs2 + (size_t)(l - 1) * H, ybuf, stats, N, nST);
        stats_final_kernel<<<1, 128, 0, stream>>>(stats, gammas + (size_t)(l - 1) * H,
                                                  betas + (size_t)(l - 1) * H, scale, shift, N);
    }

    finalize_kernel<<<2048, 256, 0, stream>>>(ybuf, scale, shift, batch, (float*)d_out, N);
}

// Round 7
// 603.250 us; speedup vs baseline: 1.5307x; 1.4175x over previous
//
#include <hip/hip_runtime.h>

constexpr int H = 128;
constexpr int F = 9;
constexpr float BN_EPS = 1e-5f;
constexpr int NBMAX = 512;      // max dst buckets (256 nodes each, N <= 131072)
constexpr int MLPB = 256;       // mlp grid size (fixed: partials slots)

typedef _Float16 f16x8 __attribute__((ext_vector_type(8)));
typedef _Float16 f16x4 __attribute__((ext_vector_type(4)));
typedef float    f32x4 __attribute__((ext_vector_type(4)));

// ---------------- bucketed CSR build (no per-node global atomics) ----------------

__global__ __launch_bounds__(256) void bucket_count_kernel(
    const int* __restrict__ dst, int* __restrict__ bcnt, int E, int nbuckets) {
    __shared__ int h[NBMAX];
    int t = threadIdx.x;
    for (int i = t; i < nbuckets; i += 256) h[i] = 0;
    __syncthreads();
    for (int i = blockIdx.x * 256 + t; i < E; i += gridDim.x * 256)
        atomicAdd(&h[dst[i] >> 8], 1);
    __syncthreads();
    for (int i = t; i < nbuckets; i += 256) {
        int c = h[i];
        if (c) atomicAdd(&bcnt[i], c);
    }
}

__global__ __launch_bounds__(NBMAX) void bucket_scan_kernel(
    const int* __restrict__ bcnt, int* __restrict__ bbase, int* __restrict__ bcur, int nbuckets) {
    __shared__ int s[NBMAX];
    int t = threadIdx.x;
    int v = (t < nbuckets) ? bcnt[t] : 0;
    s[t] = v;
    __syncthreads();
    for (int off = 1; off < NBMAX; off <<= 1) {
        int tmp = (t >= off) ? s[t - off] : 0;
        __syncthreads();
        s[t] += tmp;
        __syncthreads();
    }
    if (t < nbuckets) {
        int ex = s[t] - v;
        bbase[t] = ex;
        bcur[t] = ex;
    }
}

// Pass B: group edges by bucket; packed entry = src | ((dst&255)<<17)  (src < 2^17)
__global__ __launch_bounds__(256) void bucket_fill_kernel(
    const int* __restrict__ src, const int* __restrict__ dst, int* __restrict__ bcur,
    int* __restrict__ ebuf, int E, int nbuckets, int chunk) {
    __shared__ int h[NBMAX];
    int t = threadIdx.x;
    for (int i = t; i < nbuckets; i += 256) h[i] = 0;
    __syncthreads();
    int lo = blockIdx.x * chunk, hi = min(E, lo + chunk);
    for (int i = lo + t; i < hi; i += 256)
        atomicAdd(&h[dst[i] >> 8], 1);
    __syncthreads();
    for (int i = t; i < nbuckets; i += 256) {
        int c = h[i];
        h[i] = c ? atomicAdd(&bcur[i], c) : 0;   // h becomes block's write cursor
    }
    __syncthreads();
    for (int i = lo + t; i < hi; i += 256) {
        int d = dst[i];
        int p = atomicAdd(&h[d >> 8], 1);        // LDS atomic
        ebuf[p] = src[i] | ((d & 255) << 17);
    }
}

__global__ __launch_bounds__(256) void csr_build_kernel(
    const int* __restrict__ bbase, const int* __restrict__ bcnt,
    const int* __restrict__ ebuf, int* __restrict__ row_start,
    int* __restrict__ col, int N, int E) {
    __shared__ int hist[256];
    __shared__ int sc[256];
    int b = blockIdx.x, t = threadIdx.x;
    int beg = bbase[b], cnt = bcnt[b];
    hist[t] = 0;
    __syncthreads();
    for (int i = t; i < cnt; i += 256)
        atomicAdd(&hist[(ebuf[beg + i] >> 17) & 255], 1);
    __syncthreads();
    int v = hist[t];
    sc[t] = v;
    __syncthreads();
    for (int off = 1; off < 256; off <<= 1) {
        int tmp = (t >= off) ? sc[t - off] : 0;
        __syncthreads();
        sc[t] += tmp;
        __syncthreads();
    }
    int ex = sc[t] - v;                 // exclusive prefix within bucket
    int node = b * 256 + t;
    if (node < N) row_start[node] = beg + ex;
    hist[t] = ex;                       // becomes per-node cursor
    __syncthreads();
    for (int i = t; i < cnt; i += 256) {
        int e = ebuf[beg + i];
        int p = atomicAdd(&hist[(e >> 17) & 255], 1);   // LDS atomic
        col[beg + p] = e & 0x1FFFF;
    }
    if (b == 0 && t == 0) row_start[N] = E;
}

// ---------------- weight prep: f32 (K x 128) -> f16 in MFMA-FRAGMENT order ----------------
// slot 0: w2_0 ; slots 1..4: ws2[0..3] ; slots 5..8: ws1[0..3]
__global__ void prep_w_kernel(const float* __restrict__ w20, const float* __restrict__ ws1,
                              const float* __restrict__ ws2, _Float16* __restrict__ wf) {
    int i = blockIdx.x * blockDim.x + threadIdx.x;
    if (i >= 9 * 16384) return;
    int w = i >> 14, r = i & 16383;
    int tt = r >> 11, ks = (r >> 9) & 3, lane = (r >> 3) & 63, e = r & 7;
    int n = tt * 16 + (lane & 15);
    int k = ks * 32 + (lane >> 4) * 8 + e;
    const float* src = (w == 0) ? w20 : (w <= 4 ? ws2 + (size_t)(w - 1) * 16384
                                                : ws1 + (size_t)(w - 5) * 16384);
    wf[i] = (_Float16)src[k * H + n];
}

// pad x (N x 9 f32) -> xp (N x 16 f32, zero-padded)
__global__ void prep_x_kernel(const float* __restrict__ x, float* __restrict__ xp, int N) {
    int i = blockIdx.x * blockDim.x + threadIdx.x;
    if (i >= N * 16) return;
    int n = i >> 4, c = i & 15;
    xp[i] = (c < F) ? x[n * F + c] : 0.f;
}

// ---------------- layer 0: gather (padded F=16) + fused 9->128 linear + ReLU ----------------
__global__ __launch_bounds__(256) void gather0_kernel(
    const float* __restrict__ xp, const int* __restrict__ row_start,
    const int* __restrict__ col, const float* __restrict__ w1,
    const float* __restrict__ b1, _Float16* __restrict__ zbuf, int N) {
    int t = threadIdx.x;
    int wave = t >> 6, lane = t & 63;
    int sub = lane >> 4, li = lane & 15;
    int node = (blockIdx.x * 4 + wave) * 4 + sub;
    bool valid = node < N;
    float acc = 0.f;
    if (valid) {
        acc = xp[(size_t)node * 16 + li];
        int beg = row_start[node], end = row_start[node + 1];
        int j = beg;
        for (; j + 3 < end; j += 4) {
            int v0 = col[j], v1 = col[j + 1], v2 = col[j + 2], v3 = col[j + 3];
            float x0 = xp[(size_t)v0 * 16 + li];
            float x1 = xp[(size_t)v1 * 16 + li];
            float x2 = xp[(size_t)v2 * 16 + li];
            float x3 = xp[(size_t)v3 * 16 + li];
            acc += (x0 + x1) + (x2 + x3);
        }
        for (; j < end; ++j) acc += xp[(size_t)col[j] * 16 + li];
    }
    float y[8];
    {
        f32x4 b0 = ((const f32x4*)b1)[li * 2], b1v = ((const f32x4*)b1)[li * 2 + 1];
#pragma unroll
        for (int u = 0; u < 4; ++u) { y[u] = b0[u]; y[4 + u] = b1v[u]; }
    }
#pragma unroll
    for (int k = 0; k < F; ++k) {
        float zk = __shfl(acc, (lane & 48) | k, 64);
        f32x4 w0 = ((const f32x4*)(w1 + k * H))[li * 2];
        f32x4 w1v = ((const f32x4*)(w1 + k * H))[li * 2 + 1];
#pragma unroll
        for (int u = 0; u < 4; ++u) { y[u] += zk * w0[u]; y[4 + u] += zk * w1v[u]; }
    }
    if (valid) {
        f16x8 hz;
#pragma unroll
        for (int u = 0; u < 8; ++u) hz[u] = (_Float16)fmaxf(y[u], 0.f);
        ((f16x8*)zbuf)[(size_t)node * 16 + li] = hz;
    }
}

// ---------------- layers 1..4: gather with fused BN(prev)+ReLU on load ----------------
__global__ __launch_bounds__(256) void gather_kernel(
    const _Float16* __restrict__ y, const float* __restrict__ scale,
    const float* __restrict__ shift, const int* __restrict__ row_start,
    const int* __restrict__ col, _Float16* __restrict__ zbuf, int N) {
    int t = threadIdx.x;
    int wave = t >> 6, lane = t & 63;
    int sub = lane >> 4, li = lane & 15;
    int node = (blockIdx.x * 4 + wave) * 4 + sub;
    if (node >= N) return;
    float sc[8], sh[8];
    {
        f32x4 s0 = ((const f32x4*)scale)[li * 2], s1 = ((const f32x4*)scale)[li * 2 + 1];
        f32x4 h0 = ((const f32x4*)shift)[li * 2], h1 = ((const f32x4*)shift)[li * 2 + 1];
#pragma unroll
        for (int u = 0; u < 4; ++u) { sc[u] = s0[u]; sc[4 + u] = s1[u]; sh[u] = h0[u]; sh[4 + u] = h1[u]; }
    }
    const f16x8* yp = (const f16x8*)y;
    float a[8];
    {
        f16x8 h = yp[(size_t)node * 16 + li];
#pragma unroll
        for (int u = 0; u < 8; ++u) a[u] = fmaxf((float)h[u] * sc[u] + sh[u], 0.f);
    }
    int beg = row_start[node], end = row_start[node + 1];
    int j = beg;
    for (; j + 7 < end; j += 8) {
        int v0 = col[j], v1 = col[j + 1], v2 = col[j + 2], v3 = col[j + 3];
        int v4 = col[j + 4], v5 = col[j + 5], v6 = col[j + 6], v7 = col[j + 7];
        f16x8 h0 = yp[(size_t)v0 * 16 + li];
        f16x8 h1 = yp[(size_t)v1 * 16 + li];
        f16x8 h2 = yp[(size_t)v2 * 16 + li];
        f16x8 h3 = yp[(size_t)v3 * 16 + li];
        f16x8 h4 = yp[(size_t)v4 * 16 + li];
        f16x8 h5 = yp[(size_t)v5 * 16 + li];
        f16x8 h6 = yp[(size_t)v6 * 16 + li];
        f16x8 h7 = yp[(size_t)v7 * 16 + li];
#pragma unroll
        for (int u = 0; u < 8; ++u) {
            float p0 = fmaxf((float)h0[u] * sc[u] + sh[u], 0.f);
            float p1 = fmaxf((float)h1[u] * sc[u] + sh[u], 0.f);
            float p2 = fmaxf((float)h2[u] * sc[u] + sh[u], 0.f);
            float p3 = fmaxf((float)h3[u] * sc[u] + sh[u], 0.f);
            float p4 = fmaxf((float)h4[u] * sc[u] + sh[u], 0.f);
            float p5 = fmaxf((float)h5[u] * sc[u] + sh[u], 0.f);
            float p6 = fmaxf((float)h6[u] * sc[u] + sh[u], 0.f);
            float p7 = fmaxf((float)h7[u] * sc[u] + sh[u], 0.f);
            a[u] += ((p0 + p1) + (p2 + p3)) + ((p4 + p5) + (p6 + p7));
        }
    }
    for (; j + 3 < end; j += 4) {
        int v0 = col[j], v1 = col[j + 1], v2 = col[j + 2], v3 = col[j + 3];
        f16x8 h0 = yp[(size_t)v0 * 16 + li];
        f16x8 h1 = yp[(size_t)v1 * 16 + li];
        f16x8 h2 = yp[(size_t)v2 * 16 + li];
        f16x8 h3 = yp[(size_t)v3 * 16 + li];
#pragma unroll
        for (int u = 0; u < 8; ++u) {
            float p0 = fmaxf((float)h0[u] * sc[u] + sh[u], 0.f);
            float p1 = fmaxf((float)h1[u] * sc[u] + sh[u], 0.f);
            float p2 = fmaxf((float)h2[u] * sc[u] + sh[u], 0.f);
            float p3 = fmaxf((float)h3[u] * sc[u] + sh[u], 0.f);
            a[u] += (p0 + p1) + (p2 + p3);
        }
    }
    for (; j < end; ++j) {
        int v = col[j];
        f16x8 h = yp[(size_t)v * 16 + li];
#pragma unroll
        for (int u = 0; u < 8; ++u) a[u] += fmaxf((float)h[u] * sc[u] + sh[u], 0.f);
    }
    f16x8 hz;
#pragma unroll
    for (int u = 0; u < 8; ++u) hz[u] = (_Float16)a[u];
    ((f16x8*)zbuf)[(size_t)node * 16 + li] = hz;
}

// ---------------- fused MLP (MFMA f16, weights in LDS) + BN partials ----------------
// Persistent blocks (grid = MLPB exactly); per-block partial stats via LDS reduce +
// ONE plain store per slot. Zero global atomics.
template <bool FULL>
__global__ __launch_bounds__(512) void mlp_kernel(
    const _Float16* __restrict__ zbuf, const _Float16* __restrict__ w1f,
    const float* __restrict__ b1, const _Float16* __restrict__ w2f,
    const float* __restrict__ b2, _Float16* __restrict__ ybuf,
    float* __restrict__ partials, int N, int nST) {
    __shared__ _Float16 lds[FULL ? (32768 + 8 * 16 * 136) : 16384];
    __shared__ float red[8 * 256];
    const int t = threadIdx.x;
    const int wave = t >> 6, lane = t & 63;
    const int li = lane & 15, kg = lane >> 4;

    _Float16* wl1 = lds;
    _Float16* wl2 = FULL ? (lds + 16384) : lds;

    if constexpr (FULL) {
        const f16x8* s1 = (const f16x8*)w1f;
        const f16x8* s2 = (const f16x8*)w2f;
        f16x8* d1 = (f16x8*)wl1;
        f16x8* d2 = (f16x8*)wl2;
        for (int i = t; i < 2048; i += 512) { d1[i] = s1[i]; d2[i] = s2[i]; }
    } else {
        const f16x8* s2 = (const f16x8*)w2f;
        f16x8* d2 = (f16x8*)wl2;
        for (int i = t; i < 2048; i += 512) d2[i] = s2[i];
    }
    __syncthreads();

    float ss1[8], ss2[8];
#pragma unroll
    for (int tt = 0; tt < 8; ++tt) { ss1[tt] = 0.f; ss2[tt] = 0.f; }

    const f32x4 z4 = {0.f, 0.f, 0.f, 0.f};
    const f16x8* wf1 = (const f16x8*)wl1;
    const f16x8* wf2 = (const f16x8*)wl2;

    for (int st = blockIdx.x; st < nST; st += gridDim.x) {
        const int node0 = st * 128 + wave * 16;
        f32x4 acc2[8];

        if constexpr (FULL) {
            _Float16* y1 = lds + 32768 + wave * (16 * 136);
            f32x4 acc1[8];
#pragma unroll
            for (int tt = 0; tt < 8; ++tt) acc1[tt] = z4;
            f16x8 a[4];
#pragma unroll
            for (int ks = 0; ks < 4; ++ks)
                a[ks] = *(const f16x8*)(zbuf + (size_t)(node0 + li) * H + ks * 32 + kg * 8);
#pragma unroll
            for (int ks = 0; ks < 4; ++ks)
#pragma unroll
                for (int tt = 0; tt < 8; ++tt)
                    acc1[tt] = __builtin_amdgcn_mfma_f32_16x16x32_f16(
                        a[ks], wf1[(tt * 4 + ks) * 64 + lane], acc1[tt], 0, 0, 0);
#pragma unroll
            for (int tt = 0; tt < 8; ++tt) {
                int c = tt * 16 + li;
                float bb = b1[c];
#pragma unroll
                for (int r = 0; r < 4; ++r)
                    y1[(kg * 4 + r) * 136 + c] = (_Float16)fmaxf(acc1[tt][r] + bb, 0.f);
            }
#pragma unroll
            for (int tt = 0; tt < 8; ++tt) acc2[tt] = z4;
            f16x8 a2[4];
#pragma unroll
            for (int ks = 0; ks < 4; ++ks)
                a2[ks] = *(const f16x8*)(y1 + li * 136 + ks * 32 + kg * 8);
#pragma unroll
            for (int ks = 0; ks < 4; ++ks)
#pragma unroll
                for (int tt = 0; tt < 8; ++tt)
                    acc2[tt] = __builtin_amdgcn_mfma_f32_16x16x32_f16(
                        a2[ks], wf2[(tt * 4 + ks) * 64 + lane], acc2[tt], 0, 0, 0);
        } else {
#pragma unroll
            for (int tt = 0; tt < 8; ++tt) acc2[tt] = z4;
            f16x8 a[4];
#pragma unroll
            for (int ks = 0; ks < 4; ++ks)
                a[ks] = *(const f16x8*)(zbuf + (size_t)(node0 + li) * H + ks * 32 + kg * 8);
#pragma unroll
            for (int ks = 0; ks < 4; ++ks)
#pragma unroll
                for (int tt = 0; tt < 8; ++tt)
                    acc2[tt] = __builtin_amdgcn_mfma_f32_16x16x32_f16(
                        a[ks], wf2[(tt * 4 + ks) * 64 + lane], acc2[tt], 0, 0, 0);
        }

#pragma unroll
        for (int tt = 0; tt < 8; ++tt) {
            int c = tt * 16 + li;
            float bb = b2[c];
#pragma unroll
            for (int r = 0; r < 4; ++r) {
                int node = node0 + kg * 4 + r;
                float v = acc2[tt][r] + bb;
                if (node < N) {
                    ybuf[(size_t)node * H + c] = (_Float16)v;
                    ss1[tt] += v; ss2[tt] += v * v;
                }
            }
        }
    }

    // block-level stats reduce: wave shfl -> LDS -> one plain store per slot
#pragma unroll
    for (int tt = 0; tt < 8; ++tt) {
        float s1 = ss1[tt], s2 = ss2[tt];
        s1 += __shfl_xor(s1, 16, 64); s2 += __shfl_xor(s2, 16, 64);
        s1 += __shfl_xor(s1, 32, 64); s2 += __shfl_xor(s2, 32, 64);
        if (kg == 0) {
            red[wave * 256 + tt * 16 + li] = s1;
            red[wave * 256 + 128 + tt * 16 + li] = s2;
        }
    }
    __syncthreads();
    if (t < 256) {
        float s = 0.f;
#pragma unroll
        for (int w = 0; w < 8; ++w) s += red[w * 256 + t];
        partials[(size_t)blockIdx.x * 256 + t] = s;
    }
}

// reduce partials[MLPB][256] -> scale/shift
__global__ void stats_final_kernel(const float* __restrict__ partials,
                                   const float* __restrict__ gamma,
                                   const float* __restrict__ beta, float* __restrict__ scale,
                                   float* __restrict__ shift, int N) {
    __shared__ float sdata[256];
    int t = threadIdx.x;   // 256 threads
    float s = 0.f;
    for (int b = 0; b < MLPB; ++b) s += partials[b * 256 + t];
    sdata[t] = s;
    __syncthreads();
    if (t < 128) {
        float invN = 1.f / (float)N;
        float mean = sdata[t] * invN;
        float var = sdata[128 + t] * invN - mean * mean;
        float inv = rsqrtf(var + BN_EPS);
        float sc = gamma[t] * inv;
        scale[t] = sc;
        shift[t] = beta[t] - mean * sc;
    }
}

__global__ void finalize_kernel(const _Float16* __restrict__ ybuf, const float* __restrict__ scale,
                                const float* __restrict__ shift, const int* __restrict__ batch,
                                float* __restrict__ out, int N) {
    int nh4 = N * (H / 4);
    int total = nh4 + N;
    for (int i = blockIdx.x * blockDim.x + threadIdx.x; i < total; i += gridDim.x * blockDim.x) {
        if (i < nh4) {
            f16x4 h = ((const f16x4*)ybuf)[i];
            int c = (i & 31) * 4;
            f32x4 sc = *(const f32x4*)(scale + c);
            f32x4 sh = *(const f32x4*)(shift + c);
            f32x4 o;
#pragma unroll
            for (int u = 0; u < 4; ++u) o[u] = fmaxf((float)h[u] * sc[u] + sh[u], 0.f);
            ((f32x4*)out)[i] = o;
        } else {
            int b = i - nh4;
            out[(size_t)N * H + b] = (float)batch[b];
        }
    }
}

// ---------------- launch ----------------

extern "C" void kernel_launch(void* const* d_in, const int* in_sizes, int n_in,
                              void* d_out, int out_size, void* d_ws, size_t ws_size,
                              hipStream_t stream) {
    const float* x      = (const float*)d_in[0];
    const int*   eidx   = (const int*)d_in[1];
    const int*   batch  = (const int*)d_in[2];
    const float* w1_0   = (const float*)d_in[3];
    const float* b1_0   = (const float*)d_in[4];
    const float* w2_0   = (const float*)d_in[5];
    const float* b2_0   = (const float*)d_in[6];
    const float* gamma0 = (const float*)d_in[7];
    const float* beta0  = (const float*)d_in[8];
    const float* ws1    = (const float*)d_in[9];
    const float* bs1    = (const float*)d_in[10];
    const float* ws2    = (const float*)d_in[11];
    const float* bs2    = (const float*)d_in[12];
    const float* gammas = (const float*)d_in[13];
    const float* betas  = (const float*)d_in[14];

    const int N = in_sizes[2];
    const int E = in_sizes[1] / 2;
    const int Npad2 = (N + 127) & ~127;   // supertile-aligned
    const int* srcv = eidx;          // edge_index[0]
    const int* dstv = eidx + E;      // edge_index[1]

    char* p = (char*)d_ws;
    size_t o = 0;
    auto alloc = [&](size_t bytes) {
        void* r = p + o;
        o = (o + bytes + 255) & ~(size_t)255;
        return r;
    };
    int* col        = (int*)alloc((size_t)E * 4);
    int* row_start  = (int*)alloc((size_t)(N + 1) * 4);
    int* bcnt       = (int*)alloc(NBMAX * 4);
    int* bbase      = (int*)alloc(NBMAX * 4);
    int* bcur       = (int*)alloc(NBMAX * 4);
    _Float16* wt    = (_Float16*)alloc((size_t)9 * 16384 * 2);
    float* partials = (float*)alloc((size_t)MLPB * 256 * 4);
    float* scale    = (float*)alloc(128 * 4);
    float* shift    = (float*)alloc(128 * 4);
    float* xp       = (float*)alloc((size_t)N * 16 * 4);
    _Float16* zbuf  = (_Float16*)alloc((size_t)Npad2 * H * 2);
    _Float16* ybuf  = (_Float16*)alloc((size_t)Npad2 * H * 2);
    int* ebuf       = (int*)zbuf;   // alias: ebuf (E*4B) dead before zbuf first written
    (void)ws_size; (void)n_in; (void)out_size;

    const int nbuckets = (N + 255) >> 8;
    const int nST = Npad2 / 128;         // 128-node supertiles
    const int gblocks = (N + 15) / 16;   // 16 nodes per block
    const int fchunk = (E + 255) / 256;  // edges per bucket_fill block

    // bucketed CSR build
    hipMemsetAsync(bcnt, 0, NBMAX * 4, stream);
    bucket_count_kernel<<<256, 256, 0, stream>>>(dstv, bcnt, E, nbuckets);
    bucket_scan_kernel<<<1, NBMAX, 0, stream>>>(bcnt, bbase, bcur, nbuckets);
    bucket_fill_kernel<<<256, 256, 0, stream>>>(srcv, dstv, bcur, ebuf, E, nbuckets, fchunk);
    csr_build_kernel<<<nbuckets, 256, 0, stream>>>(bbase, bcnt, ebuf, row_start, col, N, E);

    prep_w_kernel<<<(9 * 16384 + 255) / 256, 256, 0, stream>>>(w2_0, ws1, ws2, wt);
    prep_x_kernel<<<(N * 16 + 255) / 256, 256, 0, stream>>>(x, xp, N);

    // layer 0: gather over xp with fused 9->128 linear; then half-MLP + stats
    gather0_kernel<<<gblocks, 256, 0, stream>>>(xp, row_start, col, w1_0, b1_0, zbuf, N);
    mlp_kernel<false><<<MLPB, 512, 0, stream>>>(zbuf, nullptr, nullptr, wt, b2_0, ybuf, partials, N, nST);
    stats_final_kernel<<<1, 256, 0, stream>>>(partials, gamma0, beta0, scale, shift, N);

    // layers 1..4
    for (int l = 1; l <= 4; ++l) {
        gather_kernel<<<gblocks, 256, 0, stream>>>(ybuf, scale, shift, row_start, col, zbuf, N);
        mlp_kernel<true><<<MLPB, 512, 0, stream>>>(
            zbuf, wt + (size_t)(4 + l) * 16384, bs1 + (size_t)(l - 1) * H,
            wt + (size_t)l * 16384, bs2 + (size_t)(l - 1) * H, ybuf, partials, N, nST);
        stats_final_kernel<<<1, 256, 0, stream>>>(partials, gammas + (size_t)(l - 1) * H,
                                                  betas + (size_t)(l - 1) * H, scale, shift, N);
    }

    finalize_kernel<<<2048, 256, 0, stream>>>(ybuf, scale, shift, batch, (float*)d_out, N);
}